// Round 1
// baseline (85.627 us; speedup 1.0000x reference)
//
#include <hip/hip_runtime.h>
#include <math.h>

#define NH 8

// One block, one wave. Everything in LDS; lanes 0-7 own hidden units,
// lanes 8-13 compute the 6-wide un_W outputs in parallel with the down cell.
__global__ __launch_bounds__(64) void recpolicy_kernel(
    const float* __restrict__ x,
    const float* __restrict__ up_Wih, const float* __restrict__ up_Whh,
    const float* __restrict__ up_bih, const float* __restrict__ up_bhh,
    const float* __restrict__ fc1_W, const float* __restrict__ fc1_b,
    const float* __restrict__ fc2_W, const float* __restrict__ fc2_b,
    const float* __restrict__ dn_Wih, const float* __restrict__ dn_Whh,
    const float* __restrict__ dn_bih, const float* __restrict__ dn_bhh,
    const float* __restrict__ un_W, const float* __restrict__ un_b,
    float* __restrict__ out)
{
    const int tid = threadIdx.x;
    __shared__ float s_local[4][12];   // [L][12] = concat(jl, jdl, axis=1)
    __shared__ float s_obs[13];        // obs_cat
    __shared__ float s_hup[4][NH];     // h_up
    __shared__ float s_t1[NH];
    __shared__ float s_h[NH];
    __shared__ float s_acts[24];

    // Build local[4][12] and obs_cat[13] from x (v = x[0], 57 floats).
    if (tid < 48) {
        int i = tid / 12, j = tid % 12;
        float val;
        if (j < 6) {                       // jl[i][j]
            int n = i * 6 + j;
            val = (n < 2) ? 0.f : x[n + 5];     // v[7 + (n-2)]
        } else {                           // jdl[i][j-6]
            int n = i * 6 + (j - 6);
            val = (n < 2) ? 0.f : x[n + 33];    // v[35 + (n-2)]
        }
        s_local[i][j] = val;
    }
    if (tid < 13) s_obs[tid] = (tid < 7) ? x[tid] : x[22 + tid]; // v[:7], v[29:35]
    if (tid < NH) s_hup[3][tid] = 0.f;   // h_up[3] = initial zero carry
    __syncthreads();

    // Up scan (reversed): h1=cell(local[3],0) -> s_hup[2],
    // h2=cell(local[2],h1) -> s_hup[1], h3=cell(local[1],h2) -> s_hup[0].
    if (tid < NH) {
        float a = up_bih[tid] + up_bhh[tid];
        #pragma unroll
        for (int k = 0; k < 12; ++k) a += up_Wih[tid * 12 + k] * s_local[3][k];
        s_hup[2][tid] = tanhf(a);
    }
    __syncthreads();
    if (tid < NH) {
        float a = up_bih[tid] + up_bhh[tid];
        #pragma unroll
        for (int k = 0; k < 12; ++k) a += up_Wih[tid * 12 + k] * s_local[2][k];
        #pragma unroll
        for (int k = 0; k < NH; ++k) a += up_Whh[tid * NH + k] * s_hup[2][k];
        s_hup[1][tid] = tanhf(a);
    }
    __syncthreads();
    if (tid < NH) {
        float a = up_bih[tid] + up_bhh[tid];
        #pragma unroll
        for (int k = 0; k < 12; ++k) a += up_Wih[tid * 12 + k] * s_local[1][k];
        #pragma unroll
        for (int k = 0; k < NH; ++k) a += up_Whh[tid * NH + k] * s_hup[1][k];
        s_hup[0][tid] = tanhf(a);
    }
    __syncthreads();

    // h0 = tanh(fc2_W @ tanh(fc1_W @ obs_cat + fc1_b) + fc2_b)
    if (tid < NH) {
        float a = fc1_b[tid];
        #pragma unroll
        for (int k = 0; k < 13; ++k) a += fc1_W[tid * 13 + k] * s_obs[k];
        s_t1[tid] = tanhf(a);
    }
    __syncthreads();
    if (tid < NH) {
        float a = fc2_b[tid];
        #pragma unroll
        for (int k = 0; k < NH; ++k) a += fc2_W[tid * NH + k] * s_t1[k];
        s_h[tid] = tanhf(a);
    }
    __syncthreads();

    // Down scan: act[i] = un_W @ [h; h_up[i]] + un_b ; h = cell(h_up[i], h)
    for (int i = 0; i < 4; ++i) {
        float hn = 0.f;
        if (tid < NH) {
            float a = dn_bih[tid] + dn_bhh[tid];
            #pragma unroll
            for (int k = 0; k < NH; ++k) a += dn_Wih[tid * NH + k] * s_hup[i][k];
            #pragma unroll
            for (int k = 0; k < NH; ++k) a += dn_Whh[tid * NH + k] * s_h[k];
            hn = tanhf(a);
        }
        if (tid >= 8 && tid < 14) {
            int m = tid - 8;
            float a = un_b[m];
            #pragma unroll
            for (int k = 0; k < NH; ++k) a += un_W[m * 16 + k] * s_h[k];
            #pragma unroll
            for (int k = 0; k < NH; ++k) a += un_W[m * 16 + 8 + k] * s_hup[i][k];
            s_acts[i * 6 + m] = a;
        }
        __syncthreads();                 // acts/cell read old s_h before update
        if (tid < NH) s_h[tid] = hn;
        __syncthreads();
    }

    // acts.reshape(-1)[2:]
    if (tid < 22) out[tid] = s_acts[tid + 2];
}

extern "C" void kernel_launch(void* const* d_in, const int* in_sizes, int n_in,
                              void* d_out, int out_size, void* d_ws, size_t ws_size,
                              hipStream_t stream) {
    (void)in_sizes; (void)n_in; (void)d_ws; (void)ws_size; (void)out_size;
    const float* x       = (const float*)d_in[0];
    const float* up_Wih  = (const float*)d_in[1];
    const float* up_Whh  = (const float*)d_in[2];
    const float* up_bih  = (const float*)d_in[3];
    const float* up_bhh  = (const float*)d_in[4];
    const float* fc1_W   = (const float*)d_in[5];
    const float* fc1_b   = (const float*)d_in[6];
    const float* fc2_W   = (const float*)d_in[7];
    const float* fc2_b   = (const float*)d_in[8];
    const float* dn_Wih  = (const float*)d_in[9];
    const float* dn_Whh  = (const float*)d_in[10];
    const float* dn_bih  = (const float*)d_in[11];
    const float* dn_bhh  = (const float*)d_in[12];
    const float* un_W    = (const float*)d_in[13];
    const float* un_b    = (const float*)d_in[14];
    float* out = (float*)d_out;

    recpolicy_kernel<<<1, 64, 0, stream>>>(
        x, up_Wih, up_Whh, up_bih, up_bhh,
        fc1_W, fc1_b, fc2_W, fc2_b,
        dn_Wih, dn_Whh, dn_bih, dn_bhh,
        un_W, un_b, out);
}

// Round 2
// 84.867 us; speedup vs baseline: 1.0090x; 1.0090x over previous
//
#include <hip/hip_runtime.h>
#include <math.h>

#define NH 8

// Fast tanh: sign(x) * (1 - 2/(exp(2|x|)+1)). v_exp_f32 + v_rcp_f32,
// ~1e-7 abs error; saturates correctly for large |x| (exp->inf, rcp->0).
__device__ __forceinline__ float ftanh(float v) {
    float a = __builtin_fabsf(v);
    float e = __expf(2.0f * a);
    float r = 1.0f - 2.0f * __builtin_amdgcn_rcpf(e + 1.0f);
    return __builtin_copysignf(r, v);
}

// One block, one wave. Phase 0 stages ALL weights/inputs into LDS with one
// parallel load round (the previous version paid ~10 serial HBM latencies).
// Lanes 0-7 own hidden units; lanes 16-23 run the fc1/fc2 MLP concurrently
// with the up-scan; lanes 8-13 compute un_W outputs inside the down loop.
__global__ __launch_bounds__(64) void recpolicy_kernel(
    const float* __restrict__ x,
    const float* __restrict__ up_Wih, const float* __restrict__ up_Whh,
    const float* __restrict__ up_bih, const float* __restrict__ up_bhh,
    const float* __restrict__ fc1_W, const float* __restrict__ fc1_b,
    const float* __restrict__ fc2_W, const float* __restrict__ fc2_b,
    const float* __restrict__ dn_Wih, const float* __restrict__ dn_Whh,
    const float* __restrict__ dn_bih, const float* __restrict__ dn_bhh,
    const float* __restrict__ un_W, const float* __restrict__ un_b,
    float* __restrict__ out)
{
    const int tid = threadIdx.x;

    __shared__ float s_local[4][12];   // concat(jl, jdl, axis=1)
    __shared__ float s_obs[13];        // obs_cat
    __shared__ float s_hup[4][NH];     // h_up (s_hup[3] = 0 carry)
    __shared__ float s_t1[NH];
    __shared__ float s_h2[2][NH];      // double-buffered down-scan h
    __shared__ float s_acts[24];
    __shared__ float s_upWih[NH * 12], s_upWhh[NH * NH], s_upb[NH];
    __shared__ float s_f1W[NH * 13], s_f1b[NH], s_f2W[NH * NH], s_f2b[NH];
    __shared__ float s_dnWih[NH * NH], s_dnWhh[NH * NH], s_dnb[NH];
    __shared__ float s_unW[6 * 16], s_unb[6];

    // ---- Phase 0: stage everything (all loads independent, one drain) ----
    if (tid < 48) {                       // local[4][12] from v = x[0]
        int i = tid / 12, j = tid % 12;
        float val;
        if (j < 6) {                      // jl[i][j]
            int n = i * 6 + j;
            val = (n < 2) ? 0.f : x[n + 5];
        } else {                          // jdl[i][j-6]
            int n = i * 6 + (j - 6);
            val = (n < 2) ? 0.f : x[n + 33];
        }
        s_local[i][j] = val;
    }
    if (tid < 13) s_obs[tid] = (tid < 7) ? x[tid] : x[22 + tid];
    if (tid < NH) s_hup[3][tid] = 0.f;

    { int i = tid;      s_upWih[i] = up_Wih[i]; }            // 96 (2 rounds)
    { int i = tid + 64; if (i < 96) s_upWih[i] = up_Wih[i]; }
    s_upWhh[tid] = up_Whh[tid];                              // 64
    if (tid < NH) s_upb[tid] = up_bih[tid] + up_bhh[tid];
    { int i = tid;      s_f1W[i] = fc1_W[i]; }               // 104
    { int i = tid + 64; if (i < 104) s_f1W[i] = fc1_W[i]; }
    if (tid < NH) s_f1b[tid] = fc1_b[tid];
    s_f2W[tid] = fc2_W[tid];                                 // 64
    if (tid < NH) s_f2b[tid] = fc2_b[tid];
    s_dnWih[tid] = dn_Wih[tid];                              // 64
    s_dnWhh[tid] = dn_Whh[tid];                              // 64
    if (tid < NH) s_dnb[tid] = dn_bih[tid] + dn_bhh[tid];
    { int i = tid;      s_unW[i] = un_W[i]; }                // 96
    { int i = tid + 64; if (i < 96) s_unW[i] = un_W[i]; }
    if (tid < 6) s_unb[tid] = un_b[tid];
    __syncthreads();

    // ---- Phase A: up-cell(local[3], 0) -> s_hup[2] ; fc1 on lanes 16-23 ----
    if (tid < NH) {
        float a = s_upb[tid];
        #pragma unroll
        for (int k = 0; k < 12; ++k) a += s_upWih[tid * 12 + k] * s_local[3][k];
        s_hup[2][tid] = ftanh(a);        // h=0: skip Whh term
    }
    if (tid >= 16 && tid < 24) {
        int m = tid - 16;
        float a = s_f1b[m];
        #pragma unroll
        for (int k = 0; k < 13; ++k) a += s_f1W[m * 13 + k] * s_obs[k];
        s_t1[m] = ftanh(a);
    }
    __syncthreads();

    // ---- Phase B: up-cell(local[2], h1) -> s_hup[1] ; fc2 -> s_h2[0] ----
    if (tid < NH) {
        float a = s_upb[tid];
        #pragma unroll
        for (int k = 0; k < 12; ++k) a += s_upWih[tid * 12 + k] * s_local[2][k];
        #pragma unroll
        for (int k = 0; k < NH; ++k) a += s_upWhh[tid * NH + k] * s_hup[2][k];
        s_hup[1][tid] = ftanh(a);
    }
    if (tid >= 16 && tid < 24) {
        int m = tid - 16;
        float a = s_f2b[m];
        #pragma unroll
        for (int k = 0; k < NH; ++k) a += s_f2W[m * NH + k] * s_t1[k];
        s_h2[0][m] = ftanh(a);           // h0
    }
    __syncthreads();

    // ---- Phase C: up-cell(local[1], h2) -> s_hup[0] ----
    if (tid < NH) {
        float a = s_upb[tid];
        #pragma unroll
        for (int k = 0; k < 12; ++k) a += s_upWih[tid * 12 + k] * s_local[1][k];
        #pragma unroll
        for (int k = 0; k < NH; ++k) a += s_upWhh[tid * NH + k] * s_hup[1][k];
        s_hup[0][tid] = ftanh(a);
    }
    __syncthreads();

    // ---- Down scan, 1 barrier/iter via double-buffered h ----
    #pragma unroll
    for (int i = 0; i < 4; ++i) {
        const float* hcur = s_h2[i & 1];
        if (tid < NH) {
            float a = s_dnb[tid];
            #pragma unroll
            for (int k = 0; k < NH; ++k) a += s_dnWih[tid * NH + k] * s_hup[i][k];
            #pragma unroll
            for (int k = 0; k < NH; ++k) a += s_dnWhh[tid * NH + k] * hcur[k];
            s_h2[(i + 1) & 1][tid] = ftanh(a);
        }
        if (tid >= 8 && tid < 14) {
            int m = tid - 8;
            float a = s_unb[m];
            #pragma unroll
            for (int k = 0; k < NH; ++k) a += s_unW[m * 16 + k] * hcur[k];
            #pragma unroll
            for (int k = 0; k < NH; ++k) a += s_unW[m * 16 + 8 + k] * s_hup[i][k];
            s_acts[i * 6 + m] = a;
        }
        __syncthreads();
    }

    // acts.reshape(-1)[2:]
    if (tid < 22) out[tid] = s_acts[tid + 2];
}

extern "C" void kernel_launch(void* const* d_in, const int* in_sizes, int n_in,
                              void* d_out, int out_size, void* d_ws, size_t ws_size,
                              hipStream_t stream) {
    (void)in_sizes; (void)n_in; (void)d_ws; (void)ws_size; (void)out_size;
    const float* x       = (const float*)d_in[0];
    const float* up_Wih  = (const float*)d_in[1];
    const float* up_Whh  = (const float*)d_in[2];
    const float* up_bih  = (const float*)d_in[3];
    const float* up_bhh  = (const float*)d_in[4];
    const float* fc1_W   = (const float*)d_in[5];
    const float* fc1_b   = (const float*)d_in[6];
    const float* fc2_W   = (const float*)d_in[7];
    const float* fc2_b   = (const float*)d_in[8];
    const float* dn_Wih  = (const float*)d_in[9];
    const float* dn_Whh  = (const float*)d_in[10];
    const float* dn_bih  = (const float*)d_in[11];
    const float* dn_bhh  = (const float*)d_in[12];
    const float* un_W    = (const float*)d_in[13];
    const float* un_b    = (const float*)d_in[14];
    float* out = (float*)d_out;

    recpolicy_kernel<<<1, 64, 0, stream>>>(
        x, up_Wih, up_Whh, up_bih, up_bhh,
        fc1_W, fc1_b, fc2_W, fc2_b,
        dn_Wih, dn_Whh, dn_bih, dn_bhh,
        un_W, un_b, out);
}